// Round 6
// baseline (170.842 us; speedup 1.0000x reference)
//
#include <hip/hip_runtime.h>

constexpr int Hh = 320, Ww = 320, Cc = 32, Bb = 4, Nn = 20000;
constexpr int HWp = Hh * Ww;

// Fused prep: blocks [0,800) fill grids with -1 (int4 stores, full BW);
// blocks [800,803) compute posv[dir][l][c] = pos[l] @ wv_dir.T
__global__ __launch_bounds__(256) void prep_k(
    int* __restrict__ grids, const float* __restrict__ pos,
    const float* __restrict__ in_w1, const float* __restrict__ in_w2,
    float* __restrict__ posv) {
  int bx = blockIdx.x;
  if (bx < 800) {
    int i = bx * 256 + threadIdx.x;  // int4 index; 800*256 = 204800 = 2*4*HWp/4
    ((int4*)grids)[i] = make_int4(-1, -1, -1, -1);
    return;
  }
  int t = (bx - 800) * 256 + threadIdx.x;
  if (t >= 2 * 9 * Cc) return;
  int dir = t / (9 * Cc);
  int rem = t - dir * 9 * Cc;
  int l = rem / Cc, ch = rem - l * Cc;
  const float* w = (dir == 0 ? in_w1 : in_w2) + (2 * Cc + ch) * Cc;
  const float* pl = pos + l * Cc;
  float acc = 0.f;
  for (int j = 0; j < Cc; j++) acc += pl[j] * w[j];
  posv[t] = acc;
}

// Fused: blocks [0, PROJ_TOTAL) = Q/K/V projection (register-tiled, 4 pts/thread);
// remaining blocks = build_grid scatter.
// Projection: block = 256 threads = 32 quads x 8 channel-quads; 128 points/block.
// Thread (quad, c4) computes float4 of channels [4*c4..] of Q,K,V for FOUR
// points -> 24 LDS b128 reads per point (was 48) and 1536 FMA per thread.
constexpr int PROJ_BLOCKS_PER_SB = 157;  // ceil(20000/128)
constexpr int PROJ_TOTAL = PROJ_BLOCKS_PER_SB * 8;  // 1256

__global__ __launch_bounds__(256) void project_build_k(
    const float* __restrict__ li_feats, const float* __restrict__ ra_feats,
    const int* __restrict__ li_coors, const int* __restrict__ ra_coors,
    const float* __restrict__ in_w1, const float* __restrict__ in_b1,
    const float* __restrict__ in_w2, const float* __restrict__ in_b2,
    float* __restrict__ Qh, float* __restrict__ Kp, float* __restrict__ Vp,
    int* __restrict__ grids) {
  int bx = blockIdx.x;
  if (bx >= PROJ_TOTAL) {
    int idx = (bx - PROJ_TOTAL) * 256 + threadIdx.x;
    if (idx >= 2 * Bb * Nn) return;
    int src = idx / (Bb * Nn);
    int r = idx - src * (Bb * Nn);
    int b = r / Nn, n = r - b * Nn;
    const int* c = (src == 0 ? li_coors : ra_coors) + ((size_t)b * Nn + n) * 2;
    grids[((size_t)src * Bb + b) * HWp + c[0] * Ww + c[1]] = n;
    return;
  }
  int sb = bx / PROJ_BLOCKS_PER_SB;
  int blk = bx - sb * PROJ_BLOCKS_PER_SB;
  int src = sb >> 2, b = sb & 3;
  // weights transposed, rows padded to 36 floats (9 float4) for bank spread
  __shared__ __align__(16) float wqT[32 * 36];
  __shared__ __align__(16) float wkT[32 * 36];
  __shared__ __align__(16) float wvT[32 * 36];
  __shared__ float bq[Cc];
  const float* wA = src == 0 ? in_w1 : in_w2;  // q weights: own direction
  const float* bA = src == 0 ? in_b1 : in_b2;
  const float* wB = src == 0 ? in_w2 : in_w1;  // k/v weights: other direction
  int t = threadIdx.x;
  for (int i = t; i < Cc * Cc; i += 256) {
    int c = i >> 5, j = i & 31;
    wqT[j * 36 + c] = wA[i];
    wkT[j * 36 + c] = wB[Cc * Cc + i];
    wvT[j * 36 + c] = wB[2 * Cc * Cc + i];
  }
  if (t < Cc) bq[t] = bA[t];
  __syncthreads();
  int quad = t >> 3, c4 = t & 7;
  int n0 = blk * 128 + quad * 4;
  if (n0 + 4 > Nn) n0 = Nn - 4;  // clamp: redundant idempotent work in tail block
  const float* f = (src == 0 ? li_feats : ra_feats) + ((size_t)b * Nn + n0) * Cc;
  const float4* wq4 = (const float4*)wqT;
  const float4* wk4 = (const float4*)wkT;
  const float4* wv4 = (const float4*)wvT;
  float4 bq4 = *(const float4*)(bq + c4 * 4);
  float4 aq[4], ak[4], av[4];
#pragma unroll
  for (int i = 0; i < 4; i++) {
    aq[i] = bq4;
    ak[i] = make_float4(0.f, 0.f, 0.f, 0.f);
    av[i] = make_float4(0.f, 0.f, 0.f, 0.f);
  }
#pragma unroll
  for (int j4 = 0; j4 < 8; j4++) {
    float fjs[4][4];
#pragma unroll
    for (int i = 0; i < 4; i++) {
      float4 v = ((const float4*)(f + i * Cc))[j4];
      fjs[i][0] = v.x; fjs[i][1] = v.y; fjs[i][2] = v.z; fjs[i][3] = v.w;
    }
#pragma unroll
    for (int u = 0; u < 4; u++) {
      int j = j4 * 4 + u;
      float4 q4 = wq4[j * 9 + c4];
      float4 k4 = wk4[j * 9 + c4];
      float4 v4 = wv4[j * 9 + c4];
#pragma unroll
      for (int i = 0; i < 4; i++) {
        float fj = fjs[i][u];
        aq[i].x += fj * q4.x; aq[i].y += fj * q4.y;
        aq[i].z += fj * q4.z; aq[i].w += fj * q4.w;
        ak[i].x += fj * k4.x; ak[i].y += fj * k4.y;
        ak[i].z += fj * k4.z; ak[i].w += fj * k4.w;
        av[i].x += fj * v4.x; av[i].y += fj * v4.y;
        av[i].z += fj * v4.z; av[i].w += fj * v4.w;
      }
    }
  }
  int dirq = src, dirkv = 1 - src;
  size_t qbase = (((size_t)dirq * Bb + b) * Nn + n0) * Cc + c4 * 4;
  size_t kvbase = (((size_t)dirkv * Bb + b) * Nn + n0) * Cc + c4 * 4;
#pragma unroll
  for (int i = 0; i < 4; i++) {
    *(float4*)(Qh + qbase + i * Cc) = aq[i];
    *(float4*)(Kp + kvbase + i * Cc) = ak[i];
    *(float4*)(Vp + kvbase + i * Cc) = av[i];
  }
}

// Fused attention + scatter: one pixel = 4 lanes (lane owns 8 channels).
// Eliminates the out_pts intermediate entirely. Block = 64 pixels x 4 lanes.
// Scores: 8-wide partial dots + shfl_xor(1) within the quad (head split:
// lanes 0,1 = head0 ch0-15; lanes 2,3 = head1 ch16-31). Output projection
// assembles the full 32-vector o via 3 quad shuffles (static reg indexing).
__global__ __launch_bounds__(256) void scatter_attn_k(
    const int* __restrict__ grids, const float* __restrict__ Qh,
    const float* __restrict__ Kp, const float* __restrict__ Vp,
    const float* __restrict__ posv, const float* __restrict__ in_b1,
    const float* __restrict__ in_b2, const float* __restrict__ out_w1,
    const float* __restrict__ out_b1, const float* __restrict__ out_w2,
    const float* __restrict__ out_b2, float* __restrict__ out) {
  int db = blockIdx.y;
  int dir = db >> 2, b = db & 3;
  __shared__ __align__(16) float ow[Cc * Cc];
  __shared__ __align__(16) float pv[9 * Cc];
  __shared__ float obias[Cc], bk[Cc], bv[Cc];
  const float* owp = dir == 0 ? out_w1 : out_w2;
  const float* obp = dir == 0 ? out_b1 : out_b2;
  const float* ibp = dir == 0 ? in_b1 : in_b2;
  int t = threadIdx.x;
  for (int i = t; i < Cc * Cc; i += 256) ow[i] = owp[i];
  for (int i = t; i < 9 * Cc; i += 256) pv[i] = posv[dir * 9 * Cc + i];
  if (t < Cc) { obias[t] = obp[t]; bk[t] = ibp[Cc + t]; bv[t] = ibp[2 * Cc + t]; }
  __syncthreads();
  int sub = t & 3;
  int p = blockIdx.x * 64 + (t >> 2);
  const int* gq = grids + ((size_t)dir * Bb + b) * HWp;
  int se = gq[p];
  float outv[8];
  if (se >= 0) {
    int cb = sub * 8;  // lane's channel base
    // ---- load lane's slice of qh (4 lanes cover the 128 B line)
    const float* Qb = Qh + (((size_t)dir * Bb + b) * Nn + se) * Cc + cb;
    float qh[8];
    {
      float4 a = ((const float4*)Qb)[0], c = ((const float4*)Qb)[1];
      qh[0] = a.x; qh[1] = a.y; qh[2] = a.z; qh[3] = a.w;
      qh[4] = c.x; qh[5] = c.y; qh[6] = c.z; qh[7] = c.w;
    }
    // ---- bias dot (invalid-slot score): qh . bk over lane's head
    float pb = 0.f;
#pragma unroll
    for (int k = 0; k < 8; k++) pb += qh[k] * bk[cb + k];
    pb += __shfl_xor(pb, 1);
    // ---- neighbor scores
    int y = p / Ww, x = p - (p / Ww) * Ww;
    const int* gkv = grids + ((size_t)(1 - dir) * Bb + b) * HWp;
    const int DY[9] = {0, -1, 1, 0, -1, 1, 0, -1, 1};
    const int DX[9] = {0, 0, 0, 1, 1, 1, -1, -1, -1};
    int sel[9];
    float s[9];
    const float* Kpb = Kp + ((size_t)dir * Bb + b) * Nn * Cc;
#pragma unroll
    for (int l = 0; l < 9; l++) {
      int cy = y + DY[l], cx = x + DX[l];
      int seL = -1;
      if ((unsigned)cy < (unsigned)Hh && (unsigned)cx < (unsigned)Ww)
        seL = gkv[cy * Ww + cx];
      sel[l] = seL;
      float d = 0.f;
      if (seL >= 0) {
        const float* kp = Kpb + (size_t)seL * Cc + cb;
        float4 a = ((const float4*)kp)[0], c = ((const float4*)kp)[1];
        d = qh[0] * a.x + qh[1] * a.y + qh[2] * a.z + qh[3] * a.w +
            qh[4] * c.x + qh[5] * c.y + qh[6] * c.z + qh[7] * c.w;
      }
      d += __shfl_xor(d, 1);
      s[l] = 0.25f * (pb + d);
    }
    // ---- softmax over 9 slots (lane's head; redundant in lane pairs)
    float m = s[0];
#pragma unroll
    for (int l = 1; l < 9; l++) m = fmaxf(m, s[l]);
    float sum = 0.f;
#pragma unroll
    for (int l = 0; l < 9; l++) {
      s[l] = __expf(s[l] - m);
      sum += s[l];
    }
    // ---- PV on lane's channel slice
    float o8[8];
#pragma unroll
    for (int k = 0; k < 8; k++) o8[k] = 0.f;
    const float* Vpb = Vp + ((size_t)dir * Bb + b) * Nn * Cc;
#pragma unroll
    for (int l = 0; l < 9; l++) {
      int seL = sel[l];
      if (seL >= 0) {
        const float* vp = Vpb + (size_t)seL * Cc + cb;
        float4 a = ((const float4*)vp)[0], c = ((const float4*)vp)[1];
        float w = s[l];
        const float* pvl = pv + l * Cc + cb;
        o8[0] += w * (a.x + pvl[0]); o8[1] += w * (a.y + pvl[1]);
        o8[2] += w * (a.z + pvl[2]); o8[3] += w * (a.w + pvl[3]);
        o8[4] += w * (c.x + pvl[4]); o8[5] += w * (c.y + pvl[5]);
        o8[6] += w * (c.z + pvl[6]); o8[7] += w * (c.w + pvl[7]);
      }
    }
    float r = 1.f / sum;
#pragma unroll
    for (int k = 0; k < 8; k++) o8[k] = o8[k] * r + bv[cb + k];
    // ---- assemble the other lanes' slices (static register indexing)
    float a1[8], a2[8], a3[8];
#pragma unroll
    for (int k = 0; k < 8; k++) a1[k] = __shfl_xor(o8[k], 1);
#pragma unroll
    for (int k = 0; k < 8; k++) a2[k] = __shfl_xor(o8[k], 2);
#pragma unroll
    for (int k = 0; k < 8; k++) a3[k] = __shfl_xor(a1[k], 2);
    // ---- output projection for lane's 8 channels
#pragma unroll
    for (int cc = 0; cc < 8; cc++) {
      int c = cb + cc;
      float acc = obias[c];
      const float* owr = ow + c * Cc;
      {
        int jb = sub;  // d = 0: own slice
#pragma unroll
        for (int k = 0; k < 8; k++) acc += o8[k] * owr[jb * 8 + k];
      }
      {
        int jb = sub ^ 1;
#pragma unroll
        for (int k = 0; k < 8; k++) acc += a1[k] * owr[jb * 8 + k];
      }
      {
        int jb = sub ^ 2;
#pragma unroll
        for (int k = 0; k < 8; k++) acc += a2[k] * owr[jb * 8 + k];
      }
      {
        int jb = sub ^ 3;
#pragma unroll
        for (int k = 0; k < 8; k++) acc += a3[k] * owr[jb * 8 + k];
      }
      outv[cc] = acc;
    }
  } else {
#pragma unroll
    for (int cc = 0; cc < 8; cc++) outv[cc] = 0.f;
  }
  // ---- store: for fixed cc, 16 lanes/wave write 16 consecutive floats
  float* ob = out + (((size_t)dir * Bb + b) * Cc) * HWp + p;
#pragma unroll
  for (int cc = 0; cc < 8; cc++) {
    ob[(size_t)(sub * 8 + cc) * HWp] = outv[cc];
  }
}

extern "C" void kernel_launch(void* const* d_in, const int* in_sizes, int n_in,
                              void* d_out, int out_size, void* d_ws, size_t ws_size,
                              hipStream_t stream) {
  const float* li_feats = (const float*)d_in[0];
  const int* li_coors = (const int*)d_in[1];
  const float* ra_feats = (const float*)d_in[2];
  const int* ra_coors = (const int*)d_in[3];
  const float* pos = (const float*)d_in[4];
  const float* in_w1 = (const float*)d_in[5];
  const float* in_b1 = (const float*)d_in[6];
  const float* out_w1 = (const float*)d_in[7];
  const float* out_b1 = (const float*)d_in[8];
  const float* in_w2 = (const float*)d_in[9];
  const float* in_b2 = (const float*)d_in[10];
  const float* out_w2 = (const float*)d_in[11];
  const float* out_b2 = (const float*)d_in[12];

  char* ws = (char*)d_ws;
  size_t off = 0;
  int* grids = (int*)(ws + off);
  off += (size_t)2 * Bb * HWp * 4;  // 3,276,800 B
  float* Qh = (float*)(ws + off);
  off += (size_t)2 * Bb * Nn * Cc * 4;  // 20,480,000 B
  float* Kp = (float*)(ws + off);
  off += (size_t)2 * Bb * Nn * Cc * 4;
  float* Vp = (float*)(ws + off);
  off += (size_t)2 * Bb * Nn * Cc * 4;
  float* posv = (float*)(ws + off);
  off += (size_t)2 * 9 * Cc * 4;  // total ~64.7 MB

  prep_k<<<803, 256, 0, stream>>>(grids, pos, in_w1, in_w2, posv);
  int build_blocks = (2 * Bb * Nn + 255) / 256;  // 625
  project_build_k<<<PROJ_TOTAL + build_blocks, 256, 0, stream>>>(
      li_feats, ra_feats, li_coors, ra_coors, in_w1, in_b1, in_w2, in_b2, Qh, Kp,
      Vp, grids);
  dim3 gs(HWp / 64, 2 * Bb);
  scatter_attn_k<<<gs, 256, 0, stream>>>(grids, Qh, Kp, Vp, posv, in_b1, in_b2,
                                         out_w1, out_b1, out_w2, out_b2,
                                         (float*)d_out);
}